// Round 1
// baseline (666.614 us; speedup 1.0000x reference)
//
#include <hip/hip_runtime.h>

// X: (64, 512, 4000) fp32, contiguous = 131,072,000 floats.
// D=10, STRIDE=10 -> w=400. Rows (4000) are divisible by 10, so flat:
//   out[g] = X[10g+9] / X[10g] - 2.0f,   g < 13,107,200
//
// Previous version: 4 scalar uncoalesced loads/thread (80 B lane stride) ->
// every lane request is its own 64B-line transaction (256 transactions/wave
// for 80 unique lines) -> VMEM request-rate bound (~0.9 TB/s effective).
//
// This version: stage contiguous 20 KiB tiles through LDS with fully
// coalesced float4 loads (lane i -> consecutive 16 B, 1 transaction per
// line), then each thread reads its 20-float chunk from LDS and emits a
// coalesced float2. LDS reads are 8-way bank-conflicted (20-float thread
// stride -> 8 distinct banks) but cost ~68 cyc/wave total -- hidden under
// the HBM time. 20 KiB LDS -> 8 blocks/CU -> full 32-wave occupancy.
//
// Min HBM traffic: ~524 MB read + ~52 MB write -> ~95-110 us at ~6 TB/s.

constexpr int BLOCK            = 256;
constexpr int OUTS_PER_BLOCK   = 2 * BLOCK;             // 512 outputs/block
constexpr int FLOATS_PER_BLOCK = OUTS_PER_BLOCK * 10;   // 5120 floats = 20 KiB
constexpr int VECS_PER_BLOCK   = FLOATS_PER_BLOCK / 4;  // 1280 float4
constexpr int VECS_PER_THREAD  = VECS_PER_BLOCK / BLOCK; // 5

__global__ __launch_bounds__(BLOCK) void ts_return_kernel(
    const float4* __restrict__ X4,
    float2* __restrict__ out2,
    long long n_vec4,    // total float4 in X
    long long n_out2)    // total float2 in out
{
    __shared__ float lds[FLOATS_PER_BLOCK];
    float4* lds4 = reinterpret_cast<float4*>(lds);

    const long long vbase = (long long)blockIdx.x * VECS_PER_BLOCK;

    // Coalesced staging: 5 x float4 per thread, lane-interleaved.
    #pragma unroll
    for (int i = 0; i < VECS_PER_THREAD; ++i) {
        const int v = threadIdx.x + i * BLOCK;
        if (vbase + v < n_vec4)
            lds4[v] = X4[vbase + v];
    }
    __syncthreads();

    // Each thread owns one 20-float chunk = 2 groups = 2 outputs.
    const float* p = lds + 20 * threadIdx.x;
    float2 r;
    r.x = p[9]  / p[0]  - 2.0f;
    r.y = p[19] / p[10] - 2.0f;

    const long long oidx = (long long)blockIdx.x * BLOCK + threadIdx.x;
    if (oidx < n_out2)
        out2[oidx] = r;
}

extern "C" void kernel_launch(void* const* d_in, const int* in_sizes, int n_in,
                              void* d_out, int out_size, void* d_ws, size_t ws_size,
                              hipStream_t stream) {
    const float4* X4 = (const float4*)d_in[0];
    float2* out2 = (float2*)d_out;

    const long long n_out  = (long long)out_size;   // total output floats
    const long long n_out2 = n_out / 2;             // float2 stores
    const long long n_vec4 = (n_out * 10) / 4;      // total float4 in X

    const int grid = (int)((n_out + OUTS_PER_BLOCK - 1) / OUTS_PER_BLOCK);
    ts_return_kernel<<<grid, BLOCK, 0, stream>>>(X4, out2, n_vec4, n_out2);
}